// Round 4
// baseline (11246.835 us; speedup 1.0000x reference)
//
#include <hip/hip_runtime.h>
#include <math.h>

#define BATCH   8
#define NPTS    32768
#define FDIM    32
#define NGROUP  1024
#define GSIZE   32
#define FPS_TPB 1024
#define KLANE   8       // per-lane candidate list length in KNN

// Exact float32 distance in the reference's association: ((dx^2+dy^2)+dz^2),
// with contraction blocked (__f*_rn never fuse) so bits match the numpy ref.
__device__ __forceinline__ float dist2f(float ax, float ay, float az,
                                        float bx, float by, float bz) {
  float dx = __fsub_rn(ax, bx);
  float dy = __fsub_rn(ay, by);
  float dz = __fsub_rn(az, bz);
  return __fadd_rn(__fadd_rn(__fmul_rn(dx, dx), __fmul_rn(dy, dy)),
                   __fmul_rn(dz, dz));
}

// Apply macro M to 0..31. Named scalars (not arrays) so the frontend emits
// SSA values directly -- R0-R2 showed the x[32]/y[32]/dist[32] arrays were
// never promoted out of scratch (VGPR_Count pinned at 64 across launch-bound
// settings), leaving the whole update loop spill-bound at 10.5 ms.
#define X32(M) M(0) M(1) M(2) M(3) M(4) M(5) M(6) M(7) \
               M(8) M(9) M(10) M(11) M(12) M(13) M(14) M(15) \
               M(16) M(17) M(18) M(19) M(20) M(21) M(22) M(23) \
               M(24) M(25) M(26) M(27) M(28) M(29) M(30) M(31)

// ---------------------------------------------------------------------------
// Kernel A: farthest point sampling, one block per batch.
// Per-thread state: x0..x31, y0..y31, d0..d31 in VGPRs (96), z in LDS (128 KB).
// LDS caps at 1 block/CU = 16 waves = 4 waves/SIMD; waves_per_eu(4,4)
// legalizes the 128-VGPR budget for that occupancy.
// ---------------------------------------------------------------------------
__global__
__attribute__((amdgpu_flat_work_group_size(1024, 1024)))
__attribute__((amdgpu_waves_per_eu(4, 4)))
void fps_kernel(const float* __restrict__ coord, int* __restrict__ s_idx_out) {
  __shared__ float  zbuf[NPTS];        // 128 KB
  __shared__ float  redv[16];
  __shared__ int    redp[16];
  __shared__ float4 bcastq;            // {qx, qy, qz, unused}

  const int b    = blockIdx.x;
  const int tid  = threadIdx.x;
  const int lane = tid & 63;
  const int wid  = tid >> 6;
  const float* __restrict__ c = coord + (size_t)b * NPTS * 3;
  const float3* __restrict__ c3 = (const float3*)c;

#define DECL(i) float x##i, y##i, d##i;
  X32(DECL)
#undef DECL

  // Load coords: thread owns points p = i*1024 + tid.
#define LOADP(i) { float3 v = c3[(i) * FPS_TPB + tid]; \
                   x##i = v.x; y##i = v.y; zbuf[(i) * FPS_TPB + tid] = v.z; }
  X32(LOADP)
#undef LOADP

  if (tid == 0) s_idx_out[b * NGROUP + 0] = 0;

  // Init: distance to point 0; track local argmax (ascending point index +
  // strict > keeps the lowest index on ties, matching np.argmax).
  float qx = c[0], qy = c[1], qz = c[2];
  float bestv = -1.0f; int bestp = 0;
#define INITP(i) { float t2 = dist2f(x##i, y##i, zbuf[(i) * FPS_TPB + tid], qx, qy, qz); \
                   d##i = t2; if (t2 > bestv) { bestv = t2; bestp = (i) * FPS_TPB + tid; } }
  X32(INITP)
#undef INITP

  for (int t = 1; t < NGROUP; ++t) {
    // Stage 1: wave-level argmax (max value, tie -> min index).
    float v = bestv; int p = bestp;
    #pragma unroll
    for (int m = 1; m < 64; m <<= 1) {
      float ov = __shfl_xor(v, m, 64);
      int   op = __shfl_xor(p, m, 64);
      if (ov > v || (ov == v && op < p)) { v = ov; p = op; }
    }
    if (lane == 0) { redv[wid] = v; redp[wid] = p; }
    __syncthreads();

    // Stage 2: wave 0 reduces the 16 wave candidates, fetches the winner's
    // coords, broadcasts via LDS.
    if (wid == 0) {
      float gv = redv[lane & 15]; int gp = redp[lane & 15];
      #pragma unroll
      for (int m = 1; m < 16; m <<= 1) {
        float ov = __shfl_xor(gv, m, 64);
        int   op = __shfl_xor(gp, m, 64);
        if (ov > gv || (ov == gv && op < gp)) { gv = ov; gp = op; }
      }
      if (lane == 0) {
        s_idx_out[b * NGROUP + t] = gp;
        float4 q;
        q.x = c[gp * 3 + 0]; q.y = c[gp * 3 + 1]; q.z = c[gp * 3 + 2];
        q.w = 0.0f;
        bcastq = q;
      }
    }
    __syncthreads();

    float4 q = bcastq;
    qx = q.x; qy = q.y; qz = q.z;

    // Update dists + recompute local argmax.
    bestv = -1.0f; bestp = 0;
#define UPDP(i) { float t2 = dist2f(x##i, y##i, zbuf[(i) * FPS_TPB + tid], qx, qy, qz); \
                  float nd = fminf(d##i, t2); d##i = nd; \
                  if (nd > bestv) { bestv = nd; bestp = (i) * FPS_TPB + tid; } }
    X32(UPDP)
#undef UPDP
  }
}

// ---------------------------------------------------------------------------
// Kernel B: one wave per sampled point. Brute-force 32-NN (per-lane sorted
// top-8 over its 512 strided points, then 32 wave-argmin extractions),
// then the feature-angle curvature and all 5 outputs.
// ---------------------------------------------------------------------------
__global__ __launch_bounds__(256) void knn_kernel(
    const float* __restrict__ coord, const float* __restrict__ feat,
    const int* __restrict__ labels, const int* __restrict__ s_idx_ws,
    float* __restrict__ out) {
  const int lane = threadIdx.x & 63;
  const int qid  = (blockIdx.x << 2) + (threadIdx.x >> 6);  // 0..8191
  const int b    = qid >> 10;
  const float* __restrict__ c = coord + (size_t)b * NPTS * 3;

  int sp = __builtin_amdgcn_readfirstlane(s_idx_ws[qid]);
  const int gq = b * NPTS + sp;
  const float qx = coord[(size_t)gq * 3 + 0];
  const float qy = coord[(size_t)gq * 3 + 1];
  const float qz = coord[(size_t)gq * 3 + 2];

  // Per-lane ascending top-8 (value, index), static indexing only.
  float lv[KLANE]; int li[KLANE];
  #pragma unroll
  for (int j = 0; j < KLANE; ++j) { lv[j] = 1e30f; li[j] = 0x7fffffff; }

  for (int s = 0; s < NPTS / 64; ++s) {
    int p = (s << 6) + lane;
    float3 v = ((const float3*)c)[p];
    float d2 = dist2f(v.x, v.y, v.z, qx, qy, qz);
    if (d2 < lv[KLANE - 1]) {
      // Branchless unrolled sorted insert; strict < keeps equal-distance
      // earlier (lower) indices first, matching lax.top_k tie order.
      #pragma unroll
      for (int j = KLANE - 1; j >= 1; --j) {
        bool up = d2 < lv[j - 1];
        float nv = up ? lv[j - 1] : ((d2 < lv[j]) ? d2 : lv[j]);
        int   ni = up ? li[j - 1] : ((d2 < lv[j]) ? p  : li[j]);
        lv[j] = nv; li[j] = ni;
      }
      if (d2 < lv[0]) { lv[0] = d2; li[0] = p; }
    }
  }

  // Extract the 32 globally smallest (ascending, tie -> lower index).
  // Round 0 is the query itself (d2 == 0), excluded from the angle mean
  // like angles[:, :, 1:].
  int nbp = 0;
  for (int r = 0; r < GSIZE; ++r) {
    float mv = lv[0]; int mp = li[0];
    #pragma unroll
    for (int m = 1; m < 64; m <<= 1) {
      float ov = __shfl_xor(mv, m, 64);
      int   op = __shfl_xor(mp, m, 64);
      if (ov < mv || (ov == mv && op < mp)) { mv = ov; mp = op; }
    }
    if (lane == r) nbp = mp;
    if (lv[0] == mv && li[0] == mp) {  // unique winner pops its head
      #pragma unroll
      for (int j = 0; j < KLANE - 1; ++j) { lv[j] = lv[j + 1]; li[j] = li[j + 1]; }
      lv[KLANE - 1] = 1e30f; li[KLANE - 1] = 0x7fffffff;
    }
  }

  // Angle for lanes 1..31: theta = 2*atan2(||a*|b| - |a|*b||, ||a*|b| + |a|*b||)
  const float* aRow = feat + (size_t)gq * FDIM;
  float my_a = (lane < FDIM) ? aRow[lane] : 0.0f;

  float ang = 0.0f;
  if (lane >= 1 && lane < GSIZE) {
    const float4* a4 = (const float4*)aRow;
    const float4* b4 = (const float4*)(feat + ((size_t)b * NPTS + nbp) * FDIM);
    float4 av[FDIM / 4], bv[FDIM / 4];
    float aa = 0.0f, bb = 0.0f;
    #pragma unroll
    for (int k = 0; k < FDIM / 4; ++k) {
      av[k] = a4[k]; bv[k] = b4[k];
      aa += av[k].x * av[k].x + av[k].y * av[k].y + av[k].z * av[k].z + av[k].w * av[k].w;
      bb += bv[k].x * bv[k].x + bv[k].y * bv[k].y + bv[k].z * bv[k].z + bv[k].w * bv[k].w;
    }
    float an = sqrtf(aa), bn = sqrtf(bb);
    float num2 = 0.0f, den2 = 0.0f;
    #pragma unroll
    for (int k = 0; k < FDIM / 4; ++k) {
      float n0 = av[k].x * bn - an * bv[k].x, dd0 = av[k].x * bn + an * bv[k].x;
      float n1 = av[k].y * bn - an * bv[k].y, dd1 = av[k].y * bn + an * bv[k].y;
      float n2 = av[k].z * bn - an * bv[k].z, dd2 = av[k].z * bn + an * bv[k].z;
      float n3 = av[k].w * bn - an * bv[k].w, dd3 = av[k].w * bn + an * bv[k].w;
      num2 += n0 * n0 + n1 * n1 + n2 * n2 + n3 * n3;
      den2 += dd0 * dd0 + dd1 * dd1 + dd2 * dd2 + dd3 * dd3;
    }
    ang = 2.0f * atan2f(sqrtf(num2), sqrtf(den2));
  }

  // Wave sum of the 31 angles -> p_curv everywhere.
  float tot = ang;
  #pragma unroll
  for (int m = 1; m < 64; m <<= 1) tot += __shfl_xor(tot, m, 64);
  float p_curv = tot / 31.0f;

  // Outputs (flat concatenation, all as float32).
  float* out_xyz  = out;                              // 8192*3
  float* out_feat = out + (size_t)BATCH * NGROUP * 3; // 8192*33
  float* out_sw   = out_feat + (size_t)BATCH * NGROUP * (FDIM + 1);
  float* out_lab  = out_sw  + (size_t)BATCH * NGROUP;
  float* out_sif  = out_lab + (size_t)BATCH * NGROUP;

  if (lane < FDIM)  out_feat[(size_t)qid * (FDIM + 1) + lane] = my_a;
  if (lane == FDIM) out_feat[(size_t)qid * (FDIM + 1) + FDIM] = p_curv;
  if (lane == 0) {
    out_xyz[(size_t)qid * 3 + 0] = qx;
    out_xyz[(size_t)qid * 3 + 1] = qy;
    out_xyz[(size_t)qid * 3 + 2] = qz;
    out_sw[qid]  = (p_curv > 0.087266f) ? 1.0f : 0.0f;
    out_lab[qid] = (float)labels[gq];
    out_sif[qid] = (float)gq;   // s_idx + b*N
  }
}

extern "C" void kernel_launch(void* const* d_in, const int* in_sizes, int n_in,
                              void* d_out, int out_size, void* d_ws, size_t ws_size,
                              hipStream_t stream) {
  const float* coord  = (const float*)d_in[0];
  const float* feat   = (const float*)d_in[1];
  const int*   labels = (const int*)d_in[2];
  int* s_idx_ws = (int*)d_ws;  // 8*1024 int32

  fps_kernel<<<BATCH, FPS_TPB, 0, stream>>>(coord, s_idx_ws);
  knn_kernel<<<(BATCH * NGROUP) / 4, 256, 0, stream>>>(coord, feat, labels,
                                                       s_idx_ws, (float*)d_out);
}

// Round 5
// 4817.446 us; speedup vs baseline: 2.3346x; 2.3346x over previous
//
#include <hip/hip_runtime.h>
#include <math.h>

#define BATCH   8
#define NPTS    32768
#define FDIM    32
#define NGROUP  1024
#define GSIZE   32
#define FPS_TPB 1024
#define KLANE   8       // per-lane candidate list length in KNN

// Exact float32 distance in the reference's association: ((dx^2+dy^2)+dz^2),
// with contraction blocked (__f*_rn never fuse) so bits match the numpy ref.
__device__ __forceinline__ float dist2f(float ax, float ay, float az,
                                        float bx, float by, float bz) {
  float dx = __fsub_rn(ax, bx);
  float dy = __fsub_rn(ay, by);
  float dz = __fsub_rn(az, bz);
  return __fadd_rn(__fadd_rn(__fmul_rn(dx, dx), __fmul_rn(dy, dy)),
                   __fmul_rn(dz, dz));
}

#define X32(M) M(0) M(1) M(2) M(3) M(4) M(5) M(6) M(7) \
               M(8) M(9) M(10) M(11) M(12) M(13) M(14) M(15) \
               M(16) M(17) M(18) M(19) M(20) M(21) M(22) M(23) \
               M(24) M(25) M(26) M(27) M(28) M(29) M(30) M(31)

// ---------------------------------------------------------------------------
// Kernel A: farthest point sampling, one block per batch.
// R0-R3: arch-VGPR budget is pinned at 64 by this toolchain regardless of
// launch_bounds / waves_per_eu -> any state beyond ~64 regs spills to
// scratch (L2) -> 10.5 ms. Workaround: hold the immutable x,y coords (64
// values) in the AGPR file via explicit v_accvgpr_write/read inline asm
// (register-class constraints are mandatory for the RA, unlike occupancy
// hints). dist stays in 32 named arch scalars: ~50 arch regs total < 64,
// so nothing spills. z in LDS (128 KB). Total ~50 arch + 64 acc = 114 <=
// 128 -> 16-wave block still launches at 4 waves/SIMD.
// AGPR reads are volatile so LICM can't hoist them back into VGPR live
// ranges across the t-loop.
// ---------------------------------------------------------------------------
__global__
__attribute__((amdgpu_flat_work_group_size(1024, 1024)))
__attribute__((amdgpu_waves_per_eu(4, 4)))
void fps_kernel(const float* __restrict__ coord, int* __restrict__ s_idx_out) {
  __shared__ float  zbuf[NPTS];        // 128 KB
  __shared__ float  redv[16];
  __shared__ int    redp[16];
  __shared__ float4 bcastq;            // {qx, qy, qz, unused}

  const int b    = blockIdx.x;
  const int tid  = threadIdx.x;
  const int lane = tid & 63;
  const int wid  = tid >> 6;
  const float* __restrict__ c = coord + (size_t)b * NPTS * 3;
  const float3* __restrict__ c3 = (const float3*)c;

  // AGPR-resident x,y (never modified after init); arch-resident dist.
#define DECL(i) float ax##i, ay##i, d##i;
  X32(DECL)
#undef DECL

  if (tid == 0) s_idx_out[b * NGROUP + 0] = 0;

  // Point-0 coords (uniform).
  float qx = c[0], qy = c[1], qz = c[2];
  float bestv = -1.0f; int bestp = 0;

  // Load coords, stash x,y into AGPRs, z into LDS, compute initial dist and
  // local argmax (ascending point index + strict > keeps lowest index on
  // ties, matching np.argmax).
#define LOADP(i) { \
    float3 v = c3[(i) * FPS_TPB + tid]; \
    asm volatile("v_accvgpr_write_b32 %0, %1" : "=a"(ax##i) : "v"(v.x)); \
    asm volatile("v_accvgpr_write_b32 %0, %1" : "=a"(ay##i) : "v"(v.y)); \
    zbuf[(i) * FPS_TPB + tid] = v.z; \
    float t2 = dist2f(v.x, v.y, v.z, qx, qy, qz); \
    d##i = t2; \
    if (t2 > bestv) { bestv = t2; bestp = (i) * FPS_TPB + tid; } }
  X32(LOADP)
#undef LOADP

  for (int t = 1; t < NGROUP; ++t) {
    // Stage 1: wave-level argmax (max value, tie -> min index).
    float v = bestv; int p = bestp;
    #pragma unroll
    for (int m = 1; m < 64; m <<= 1) {
      float ov = __shfl_xor(v, m, 64);
      int   op = __shfl_xor(p, m, 64);
      if (ov > v || (ov == v && op < p)) { v = ov; p = op; }
    }
    if (lane == 0) { redv[wid] = v; redp[wid] = p; }
    __syncthreads();

    // Stage 2: wave 0 reduces the 16 wave candidates, fetches the winner's
    // coords, broadcasts via LDS.
    if (wid == 0) {
      float gv = redv[lane & 15]; int gp = redp[lane & 15];
      #pragma unroll
      for (int m = 1; m < 16; m <<= 1) {
        float ov = __shfl_xor(gv, m, 64);
        int   op = __shfl_xor(gp, m, 64);
        if (ov > gv || (ov == gv && op < gp)) { gv = ov; gp = op; }
      }
      if (lane == 0) {
        s_idx_out[b * NGROUP + t] = gp;
        float4 q;
        q.x = c[gp * 3 + 0]; q.y = c[gp * 3 + 1]; q.z = c[gp * 3 + 2];
        q.w = 0.0f;
        bcastq = q;
      }
    }
    __syncthreads();

    float4 q = bcastq;
    qx = q.x; qy = q.y; qz = q.z;

    // Update dists + recompute local argmax. x,y read back from AGPRs
    // (volatile: pinned inside the loop, 2 VALU ops each).
    bestv = -1.0f; bestp = 0;
#define UPDP(i) { \
    float xi, yi; \
    asm volatile("v_accvgpr_read_b32 %0, %1" : "=v"(xi) : "a"(ax##i)); \
    asm volatile("v_accvgpr_read_b32 %0, %1" : "=v"(yi) : "a"(ay##i)); \
    float t2 = dist2f(xi, yi, zbuf[(i) * FPS_TPB + tid], qx, qy, qz); \
    float nd = fminf(d##i, t2); d##i = nd; \
    if (nd > bestv) { bestv = nd; bestp = (i) * FPS_TPB + tid; } }
    X32(UPDP)
#undef UPDP
  }
}

// ---------------------------------------------------------------------------
// Kernel B: one wave per sampled point. Brute-force 32-NN (per-lane sorted
// top-8 over its 512 strided points, then 32 wave-argmin extractions),
// then the feature-angle curvature and all 5 outputs.
// ---------------------------------------------------------------------------
__global__ __launch_bounds__(256) void knn_kernel(
    const float* __restrict__ coord, const float* __restrict__ feat,
    const int* __restrict__ labels, const int* __restrict__ s_idx_ws,
    float* __restrict__ out) {
  const int lane = threadIdx.x & 63;
  const int qid  = (blockIdx.x << 2) + (threadIdx.x >> 6);  // 0..8191
  const int b    = qid >> 10;
  const float* __restrict__ c = coord + (size_t)b * NPTS * 3;

  int sp = __builtin_amdgcn_readfirstlane(s_idx_ws[qid]);
  const int gq = b * NPTS + sp;
  const float qx = coord[(size_t)gq * 3 + 0];
  const float qy = coord[(size_t)gq * 3 + 1];
  const float qz = coord[(size_t)gq * 3 + 2];

  // Per-lane ascending top-8 (value, index), static indexing only.
  float lv[KLANE]; int li[KLANE];
  #pragma unroll
  for (int j = 0; j < KLANE; ++j) { lv[j] = 1e30f; li[j] = 0x7fffffff; }

  for (int s = 0; s < NPTS / 64; ++s) {
    int p = (s << 6) + lane;
    float3 v = ((const float3*)c)[p];
    float d2 = dist2f(v.x, v.y, v.z, qx, qy, qz);
    if (d2 < lv[KLANE - 1]) {
      // Branchless unrolled sorted insert; strict < keeps equal-distance
      // earlier (lower) indices first, matching lax.top_k tie order.
      #pragma unroll
      for (int j = KLANE - 1; j >= 1; --j) {
        bool up = d2 < lv[j - 1];
        float nv = up ? lv[j - 1] : ((d2 < lv[j]) ? d2 : lv[j]);
        int   ni = up ? li[j - 1] : ((d2 < lv[j]) ? p  : li[j]);
        lv[j] = nv; li[j] = ni;
      }
      if (d2 < lv[0]) { lv[0] = d2; li[0] = p; }
    }
  }

  // Extract the 32 globally smallest (ascending, tie -> lower index).
  // Round 0 is the query itself (d2 == 0), excluded from the angle mean
  // like angles[:, :, 1:].
  int nbp = 0;
  for (int r = 0; r < GSIZE; ++r) {
    float mv = lv[0]; int mp = li[0];
    #pragma unroll
    for (int m = 1; m < 64; m <<= 1) {
      float ov = __shfl_xor(mv, m, 64);
      int   op = __shfl_xor(mp, m, 64);
      if (ov < mv || (ov == mv && op < mp)) { mv = ov; mp = op; }
    }
    if (lane == r) nbp = mp;
    if (lv[0] == mv && li[0] == mp) {  // unique winner pops its head
      #pragma unroll
      for (int j = 0; j < KLANE - 1; ++j) { lv[j] = lv[j + 1]; li[j] = li[j + 1]; }
      lv[KLANE - 1] = 1e30f; li[KLANE - 1] = 0x7fffffff;
    }
  }

  // Angle for lanes 1..31: theta = 2*atan2(||a*|b| - |a|*b||, ||a*|b| + |a|*b||)
  const float* aRow = feat + (size_t)gq * FDIM;
  float my_a = (lane < FDIM) ? aRow[lane] : 0.0f;

  float ang = 0.0f;
  if (lane >= 1 && lane < GSIZE) {
    const float4* a4 = (const float4*)aRow;
    const float4* b4 = (const float4*)(feat + ((size_t)b * NPTS + nbp) * FDIM);
    float4 av[FDIM / 4], bv[FDIM / 4];
    float aa = 0.0f, bb = 0.0f;
    #pragma unroll
    for (int k = 0; k < FDIM / 4; ++k) {
      av[k] = a4[k]; bv[k] = b4[k];
      aa += av[k].x * av[k].x + av[k].y * av[k].y + av[k].z * av[k].z + av[k].w * av[k].w;
      bb += bv[k].x * bv[k].x + bv[k].y * bv[k].y + bv[k].z * bv[k].z + bv[k].w * bv[k].w;
    }
    float an = sqrtf(aa), bn = sqrtf(bb);
    float num2 = 0.0f, den2 = 0.0f;
    #pragma unroll
    for (int k = 0; k < FDIM / 4; ++k) {
      float n0 = av[k].x * bn - an * bv[k].x, dd0 = av[k].x * bn + an * bv[k].x;
      float n1 = av[k].y * bn - an * bv[k].y, dd1 = av[k].y * bn + an * bv[k].y;
      float n2 = av[k].z * bn - an * bv[k].z, dd2 = av[k].z * bn + an * bv[k].z;
      float n3 = av[k].w * bn - an * bv[k].w, dd3 = av[k].w * bn + an * bv[k].w;
      num2 += n0 * n0 + n1 * n1 + n2 * n2 + n3 * n3;
      den2 += dd0 * dd0 + dd1 * dd1 + dd2 * dd2 + dd3 * dd3;
    }
    ang = 2.0f * atan2f(sqrtf(num2), sqrtf(den2));
  }

  // Wave sum of the 31 angles -> p_curv everywhere.
  float tot = ang;
  #pragma unroll
  for (int m = 1; m < 64; m <<= 1) tot += __shfl_xor(tot, m, 64);
  float p_curv = tot / 31.0f;

  // Outputs (flat concatenation, all as float32).
  float* out_xyz  = out;                              // 8192*3
  float* out_feat = out + (size_t)BATCH * NGROUP * 3; // 8192*33
  float* out_sw   = out_feat + (size_t)BATCH * NGROUP * (FDIM + 1);
  float* out_lab  = out_sw  + (size_t)BATCH * NGROUP;
  float* out_sif  = out_lab + (size_t)BATCH * NGROUP;

  if (lane < FDIM)  out_feat[(size_t)qid * (FDIM + 1) + lane] = my_a;
  if (lane == FDIM) out_feat[(size_t)qid * (FDIM + 1) + FDIM] = p_curv;
  if (lane == 0) {
    out_xyz[(size_t)qid * 3 + 0] = qx;
    out_xyz[(size_t)qid * 3 + 1] = qy;
    out_xyz[(size_t)qid * 3 + 2] = qz;
    out_sw[qid]  = (p_curv > 0.087266f) ? 1.0f : 0.0f;
    out_lab[qid] = (float)labels[gq];
    out_sif[qid] = (float)gq;   // s_idx + b*N
  }
}

extern "C" void kernel_launch(void* const* d_in, const int* in_sizes, int n_in,
                              void* d_out, int out_size, void* d_ws, size_t ws_size,
                              hipStream_t stream) {
  const float* coord  = (const float*)d_in[0];
  const float* feat   = (const float*)d_in[1];
  const int*   labels = (const int*)d_in[2];
  int* s_idx_ws = (int*)d_ws;  // 8*1024 int32

  fps_kernel<<<BATCH, FPS_TPB, 0, stream>>>(coord, s_idx_ws);
  knn_kernel<<<(BATCH * NGROUP) / 4, 256, 0, stream>>>(coord, feat, labels,
                                                       s_idx_ws, (float*)d_out);
}

// Round 6
// 3160.556 us; speedup vs baseline: 3.5585x; 1.5242x over previous
//
#include <hip/hip_runtime.h>
#include <math.h>

#define BATCH   8
#define NPTS    32768
#define FDIM    32
#define NGROUP  1024
#define GSIZE   32
#define KLANE   8       // per-lane candidate list length in KNN

// Multi-block FPS config: 8 blocks/batch x 512 threads x 8 pts/thread = 32768.
#define NBLK    8
#define FTPB    512
#define CHUNK   (NPTS / NBLK)   // 4096 points per block

// Exact float32 distance in the reference's association: ((dx^2+dy^2)+dz^2),
// contraction blocked so bits match the numpy ref (argmax stability).
__device__ __forceinline__ float dist2f(float ax, float ay, float az,
                                        float bx, float by, float bz) {
  float dx = __fsub_rn(ax, bx);
  float dy = __fsub_rn(ay, by);
  float dz = __fsub_rn(az, bz);
  return __fadd_rn(__fadd_rn(__fmul_rn(dx, dx), __fmul_rn(dy, dy)),
                   __fmul_rn(dz, dz));
}

#define X8(M) M(0) M(1) M(2) M(3) M(4) M(5) M(6) M(7)

// ---------------------------------------------------------------------------
// Kernel A: farthest point sampling, 8 blocks per batch (64 blocks total).
// Per-thread state: 8 points as named scalars (x,y,z,d = 32 regs; total
// demand ~50 < the 64-VGPR cap this toolchain pins us to -> no spills).
// Cross-block sync per iteration: each block atomically publishes a packed
// candidate (tag<<47 | distbits<<15 | (0x7FFF-idx)) to its own slot, then
// polls all 8 slots of its batch for tag==t. Max over packed values =
// global argmax with numpy tie-break (min index). Slots ping-pong on t&1
// so a fast block's t+1 store can't clobber a value a slow block still
// needs at t (a t+2 write to the same parity requires all blocks >= t+1).
// ---------------------------------------------------------------------------
__global__ __launch_bounds__(FTPB) void fps_kernel(
    const float* __restrict__ coord,
    unsigned long long* __restrict__ slots,   // [2][BATCH*NBLK], pre-zeroed
    int* __restrict__ s_idx_out) {
  const int gb   = blockIdx.x;        // 0..63
  const int b    = gb >> 3;           // batch
  const int bk   = gb & 7;            // block within batch
  const int tid  = threadIdx.x;
  const int lane = tid & 63;
  const int wid  = tid >> 6;          // 0..7
  const float* __restrict__ c = coord + (size_t)b * NPTS * 3;
  const float3* __restrict__ c3 = (const float3*)c;

  __shared__ float redv[8];
  __shared__ int   redp[8];
  __shared__ unsigned long long bcast;

  const int pbase = bk * CHUNK + tid; // + i*FTPB

#define DECL8(i) float x##i, y##i, z##i, d##i;
  X8(DECL8)
#undef DECL8

  // Init: load owned points, distance to batch point 0, local argmax
  // (ascending point index + strict > == np.argmax lowest-index tie-break).
  float qx = c[0], qy = c[1], qz = c[2];
  float bestv = -1.0f; int bestp = 0;
#define LOAD8(i) { int p = pbase + (i) * FTPB; float3 v = c3[p];            \
    x##i = v.x; y##i = v.y; z##i = v.z;                                      \
    float t2 = dist2f(v.x, v.y, v.z, qx, qy, qz); d##i = t2;                 \
    if (t2 > bestv) { bestv = t2; bestp = p; } }
  X8(LOAD8)
#undef LOAD8

  if (bk == 0 && tid == 0) s_idx_out[b * NGROUP + 0] = 0;

  for (int t = 1; t < NGROUP; ++t) {
    // Wave-level argmax (max value, tie -> min index).
    float v = bestv; int p = bestp;
    #pragma unroll
    for (int m = 1; m < 64; m <<= 1) {
      float ov = __shfl_xor(v, m, 64);
      int   op = __shfl_xor(p, m, 64);
      if (ov > v || (ov == v && op < p)) { v = ov; p = op; }
    }
    if (lane == 0) { redv[wid] = v; redp[wid] = p; }
    __syncthreads();   // B1

    if (wid == 0) {
      // Block-level argmax over the 8 wave candidates (replicated butterfly).
      float gv = redv[lane & 7]; int gp = redp[lane & 7];
      #pragma unroll
      for (int m = 1; m < 8; m <<= 1) {
        float ov = __shfl_xor(gv, m, 64);
        int   op = __shfl_xor(gp, m, 64);
        if (ov > gv || (ov == gv && op < gp)) { gv = ov; gp = op; }
      }
      unsigned long long* base = slots + (size_t)(t & 1) * (BATCH * NBLK);
      if (lane == 0) {
        unsigned long long pk = ((unsigned long long)t << 47)
                              | ((unsigned long long)__float_as_uint(gv) << 15)
                              | (unsigned long long)(0x7FFF - gp);
        __hip_atomic_store(base + gb, pk, __ATOMIC_RELEASE,
                           __HIP_MEMORY_SCOPE_AGENT);
      }
      // Poll: lanes 0..7 each watch one slot of this batch until tag == t.
      unsigned long long pk2 = 0;
      if (lane < 8) {
        const unsigned long long* sl = base + (b << 3) + lane;
        do {
          pk2 = __hip_atomic_load(sl, __ATOMIC_ACQUIRE,
                                  __HIP_MEMORY_SCOPE_AGENT);
        } while ((int)(pk2 >> 47) != t);
      }
      #pragma unroll
      for (int m = 1; m < 8; m <<= 1) {
        unsigned long long o = __shfl_xor(pk2, m, 64);
        if (o > pk2) pk2 = o;
      }
      if (lane == 0) bcast = pk2;
    }
    __syncthreads();   // B2

    const unsigned long long wpk = bcast;
    const int gp = 0x7FFF - (int)(wpk & 0x7FFF);
    if (bk == 0 && tid == 0) s_idx_out[b * NGROUP + t] = gp;
    if (t == NGROUP - 1) break;

    // Fetch winner coords (same-address wave load, L2-resident) and update.
    float3 q = c3[gp];
    qx = q.x; qy = q.y; qz = q.z;
    bestv = -1.0f; bestp = 0;
#define UPD8(i) { float t2 = dist2f(x##i, y##i, z##i, qx, qy, qz);           \
    float nd = fminf(d##i, t2); d##i = nd;                                   \
    if (nd > bestv) { bestv = nd; bestp = pbase + (i) * FTPB; } }
    X8(UPD8)
#undef UPD8
  }
}

// ---------------------------------------------------------------------------
// Kernel B: one wave per sampled point. Brute-force 32-NN (per-lane sorted
// top-8 over its 512 strided points, then 32 wave-argmin extractions),
// then the feature-angle curvature and all 5 outputs.
// ---------------------------------------------------------------------------
__global__ __launch_bounds__(256) void knn_kernel(
    const float* __restrict__ coord, const float* __restrict__ feat,
    const int* __restrict__ labels, const int* __restrict__ s_idx_ws,
    float* __restrict__ out) {
  const int lane = threadIdx.x & 63;
  const int qid  = (blockIdx.x << 2) + (threadIdx.x >> 6);  // 0..8191
  const int b    = qid >> 10;
  const float* __restrict__ c = coord + (size_t)b * NPTS * 3;

  int sp = __builtin_amdgcn_readfirstlane(s_idx_ws[qid]);
  const int gq = b * NPTS + sp;
  const float qx = coord[(size_t)gq * 3 + 0];
  const float qy = coord[(size_t)gq * 3 + 1];
  const float qz = coord[(size_t)gq * 3 + 2];

  // Per-lane ascending top-8 (value, index), static indexing only.
  float lv[KLANE]; int li[KLANE];
  #pragma unroll
  for (int j = 0; j < KLANE; ++j) { lv[j] = 1e30f; li[j] = 0x7fffffff; }

  for (int s = 0; s < NPTS / 64; ++s) {
    int p = (s << 6) + lane;
    float3 v = ((const float3*)c)[p];
    float d2 = dist2f(v.x, v.y, v.z, qx, qy, qz);
    if (d2 < lv[KLANE - 1]) {
      // Branchless unrolled sorted insert; strict < keeps equal-distance
      // earlier (lower) indices first, matching lax.top_k tie order.
      #pragma unroll
      for (int j = KLANE - 1; j >= 1; --j) {
        bool up = d2 < lv[j - 1];
        float nv = up ? lv[j - 1] : ((d2 < lv[j]) ? d2 : lv[j]);
        int   ni = up ? li[j - 1] : ((d2 < lv[j]) ? p  : li[j]);
        lv[j] = nv; li[j] = ni;
      }
      if (d2 < lv[0]) { lv[0] = d2; li[0] = p; }
    }
  }

  // Extract the 32 globally smallest (ascending, tie -> lower index).
  // Round 0 is the query itself (d2 == 0), excluded from the angle mean
  // like angles[:, :, 1:].
  int nbp = 0;
  for (int r = 0; r < GSIZE; ++r) {
    float mv = lv[0]; int mp = li[0];
    #pragma unroll
    for (int m = 1; m < 64; m <<= 1) {
      float ov = __shfl_xor(mv, m, 64);
      int   op = __shfl_xor(mp, m, 64);
      if (ov < mv || (ov == mv && op < mp)) { mv = ov; mp = op; }
    }
    if (lane == r) nbp = mp;
    if (lv[0] == mv && li[0] == mp) {  // unique winner pops its head
      #pragma unroll
      for (int j = 0; j < KLANE - 1; ++j) { lv[j] = lv[j + 1]; li[j] = li[j + 1]; }
      lv[KLANE - 1] = 1e30f; li[KLANE - 1] = 0x7fffffff;
    }
  }

  // Angle for lanes 1..31: theta = 2*atan2(||a*|b| - |a|*b||, ||a*|b| + |a|*b||)
  const float* aRow = feat + (size_t)gq * FDIM;
  float my_a = (lane < FDIM) ? aRow[lane] : 0.0f;

  float ang = 0.0f;
  if (lane >= 1 && lane < GSIZE) {
    const float4* a4 = (const float4*)aRow;
    const float4* b4 = (const float4*)(feat + ((size_t)b * NPTS + nbp) * FDIM);
    float4 av[FDIM / 4], bv[FDIM / 4];
    float aa = 0.0f, bb = 0.0f;
    #pragma unroll
    for (int k = 0; k < FDIM / 4; ++k) {
      av[k] = a4[k]; bv[k] = b4[k];
      aa += av[k].x * av[k].x + av[k].y * av[k].y + av[k].z * av[k].z + av[k].w * av[k].w;
      bb += bv[k].x * bv[k].x + bv[k].y * bv[k].y + bv[k].z * bv[k].z + bv[k].w * bv[k].w;
    }
    float an = sqrtf(aa), bn = sqrtf(bb);
    float num2 = 0.0f, den2 = 0.0f;
    #pragma unroll
    for (int k = 0; k < FDIM / 4; ++k) {
      float n0 = av[k].x * bn - an * bv[k].x, dd0 = av[k].x * bn + an * bv[k].x;
      float n1 = av[k].y * bn - an * bv[k].y, dd1 = av[k].y * bn + an * bv[k].y;
      float n2 = av[k].z * bn - an * bv[k].z, dd2 = av[k].z * bn + an * bv[k].z;
      float n3 = av[k].w * bn - an * bv[k].w, dd3 = av[k].w * bn + an * bv[k].w;
      num2 += n0 * n0 + n1 * n1 + n2 * n2 + n3 * n3;
      den2 += dd0 * dd0 + dd1 * dd1 + dd2 * dd2 + dd3 * dd3;
    }
    ang = 2.0f * atan2f(sqrtf(num2), sqrtf(den2));
  }

  // Wave sum of the 31 angles -> p_curv everywhere.
  float tot = ang;
  #pragma unroll
  for (int m = 1; m < 64; m <<= 1) tot += __shfl_xor(tot, m, 64);
  float p_curv = tot / 31.0f;

  // Outputs (flat concatenation, all as float32).
  float* out_xyz  = out;                              // 8192*3
  float* out_feat = out + (size_t)BATCH * NGROUP * 3; // 8192*33
  float* out_sw   = out_feat + (size_t)BATCH * NGROUP * (FDIM + 1);
  float* out_lab  = out_sw  + (size_t)BATCH * NGROUP;
  float* out_sif  = out_lab + (size_t)BATCH * NGROUP;

  if (lane < FDIM)  out_feat[(size_t)qid * (FDIM + 1) + lane] = my_a;
  if (lane == FDIM) out_feat[(size_t)qid * (FDIM + 1) + FDIM] = p_curv;
  if (lane == 0) {
    out_xyz[(size_t)qid * 3 + 0] = qx;
    out_xyz[(size_t)qid * 3 + 1] = qy;
    out_xyz[(size_t)qid * 3 + 2] = qz;
    out_sw[qid]  = (p_curv > 0.087266f) ? 1.0f : 0.0f;
    out_lab[qid] = (float)labels[gq];
    out_sif[qid] = (float)gq;   // s_idx + b*N
  }
}

extern "C" void kernel_launch(void* const* d_in, const int* in_sizes, int n_in,
                              void* d_out, int out_size, void* d_ws, size_t ws_size,
                              hipStream_t stream) {
  const float* coord  = (const float*)d_in[0];
  const float* feat   = (const float*)d_in[1];
  const int*   labels = (const int*)d_in[2];

  // ws layout: [2][64] u64 ping-pong slots (zeroed), then 8*1024 int s_idx.
  unsigned long long* slots = (unsigned long long*)d_ws;
  int* s_idx_ws = (int*)((char*)d_ws + 2 * BATCH * NBLK * sizeof(unsigned long long));

  hipMemsetAsync(d_ws, 0, 2 * BATCH * NBLK * sizeof(unsigned long long), stream);
  fps_kernel<<<BATCH * NBLK, FTPB, 0, stream>>>(coord, slots, s_idx_ws);
  knn_kernel<<<(BATCH * NGROUP) / 4, 256, 0, stream>>>(coord, feat, labels,
                                                       s_idx_ws, (float*)d_out);
}